// Round 1
// baseline (386.947 us; speedup 1.0000x reference)
//
#include <hip/hip_runtime.h>
#include <hip/hip_bf16.h>
#include <stdint.h>

typedef __bf16 bf16_t;
typedef __bf16 bf16x8 __attribute__((ext_vector_type(8)));
typedef float f32x4 __attribute__((ext_vector_type(4)));

#define TILE 128
#define BK 32

// NT GEMM: C[m,n] = op( sum_k A[m,k]*B[n,k] + bias )
// A: M x K row-major (k contiguous), B: N x K row-major (k contiguous).
// 128x128 tile per block, 256 threads = 4 waves in 2x2, each wave 64x64
// via 4x4 grid of 16x16x32 bf16 MFMAs. BK=32 (one MFMA K-step per tile).
// BIAS_MODE: 0=none, 1=bias[col], 2=bias[row]
template<bool A_F32, bool B_F32, bool OUT_F32, bool RELU, int BIAS_MODE>
__global__ __launch_bounds__(256, 2)
void gemm_nt(const void* __restrict__ Ap, const void* __restrict__ Bp,
             const float* __restrict__ bias, void* __restrict__ Cp,
             int M, int N, int K,
             long sAb, long sBb, long sCb, int ldc)
{
    __shared__ bf16_t As[TILE * BK];
    __shared__ bf16_t Bs[TILE * BK];

    const int b      = blockIdx.z;
    const int blockM = blockIdx.y * TILE;
    const int blockN = blockIdx.x * TILE;
    const int t      = threadIdx.x;

    // staging: thread t covers row t>>1 (0..127), 16 cols at (t&1)*16
    const int srow  = t >> 1;
    const int shalf = (t & 1) * 16;

    const int wave = t >> 6;
    const int lane = t & 63;
    const int wm   = (wave >> 1) * 64;   // wave m-origin in tile
    const int wn   = (wave & 1) * 64;    // wave n-origin in tile
    const int fr   = lane & 15;          // fragment row (m for A, n for B)
    const int fk   = (lane >> 4) * 8;    // fragment k offset
    const int quad = lane >> 4;

    f32x4 acc[4][4] = {};

    const float*  Af = (const float*) Ap + sAb * (long)b;
    const bf16_t* Ah = (const bf16_t*)Ap + sAb * (long)b;
    const float*  Bf = (const float*) Bp + sBb * (long)b;
    const bf16_t* Bh = (const bf16_t*)Bp + sBb * (long)b;

    for (int k0 = 0; k0 < K; k0 += BK) {
        // ---- stage A tile ----
        {
            bf16_t* dst = &As[srow * BK + shalf];
            if (A_F32) {
                const float* src = Af + (long)(blockM + srow) * K + k0 + shalf;
                alignas(16) bf16_t tmp[16];
                #pragma unroll
                for (int c = 0; c < 16; c += 4) {
                    float4 vv = *(const float4*)(src + c);
                    tmp[c+0] = (bf16_t)vv.x; tmp[c+1] = (bf16_t)vv.y;
                    tmp[c+2] = (bf16_t)vv.z; tmp[c+3] = (bf16_t)vv.w;
                }
                ((uint4*)dst)[0] = ((const uint4*)tmp)[0];
                ((uint4*)dst)[1] = ((const uint4*)tmp)[1];
            } else {
                const bf16_t* src = Ah + (long)(blockM + srow) * K + k0 + shalf;
                ((uint4*)dst)[0] = ((const uint4*)src)[0];
                ((uint4*)dst)[1] = ((const uint4*)src)[1];
            }
        }
        // ---- stage B tile ----
        {
            bf16_t* dst = &Bs[srow * BK + shalf];
            if (B_F32) {
                const float* src = Bf + (long)(blockN + srow) * K + k0 + shalf;
                alignas(16) bf16_t tmp[16];
                #pragma unroll
                for (int c = 0; c < 16; c += 4) {
                    float4 vv = *(const float4*)(src + c);
                    tmp[c+0] = (bf16_t)vv.x; tmp[c+1] = (bf16_t)vv.y;
                    tmp[c+2] = (bf16_t)vv.z; tmp[c+3] = (bf16_t)vv.w;
                }
                ((uint4*)dst)[0] = ((const uint4*)tmp)[0];
                ((uint4*)dst)[1] = ((const uint4*)tmp)[1];
            } else {
                const bf16_t* src = Bh + (long)(blockN + srow) * K + k0 + shalf;
                ((uint4*)dst)[0] = ((const uint4*)src)[0];
                ((uint4*)dst)[1] = ((const uint4*)src)[1];
            }
        }
        __syncthreads();

        bf16x8 afr[4], bfr[4];
        #pragma unroll
        for (int i = 0; i < 4; i++)
            afr[i] = *(const bf16x8*)&As[(wm + i*16 + fr) * BK + fk];
        #pragma unroll
        for (int j = 0; j < 4; j++)
            bfr[j] = *(const bf16x8*)&Bs[(wn + j*16 + fr) * BK + fk];

        #pragma unroll
        for (int i = 0; i < 4; i++)
            #pragma unroll
            for (int j = 0; j < 4; j++)
                acc[i][j] = __builtin_amdgcn_mfma_f32_16x16x32_bf16(
                                afr[i], bfr[j], acc[i][j], 0, 0, 0);
        __syncthreads();
    }

    // ---- epilogue ----
    float*  Cf = (float*) Cp + sCb * (long)b;
    bf16_t* Ch = (bf16_t*)Cp + sCb * (long)b;
    #pragma unroll
    for (int i = 0; i < 4; i++) {
        #pragma unroll
        for (int j = 0; j < 4; j++) {
            const int gcol = blockN + wn + j*16 + fr;
            float bcol = 0.f;
            if (BIAS_MODE == 1) bcol = bias[gcol];
            #pragma unroll
            for (int r = 0; r < 4; r++) {
                const int grow = blockM + wm + i*16 + quad*4 + r;
                float v = acc[i][j][r];
                if (BIAS_MODE == 1) v += bcol;
                if (BIAS_MODE == 2) v += bias[grow];
                if (RELU) v = fmaxf(v, 0.f);
                if (OUT_F32) Cf[(long)grow * ldc + gcol] = v;
                else         Ch[(long)grow * ldc + gcol] = (bf16_t)v;
            }
        }
    }
}

extern "C" void kernel_launch(void* const* d_in, const int* in_sizes, int n_in,
                              void* d_out, int out_size, void* d_ws, size_t ws_size,
                              hipStream_t stream)
{
    const float* q   = (const float*)d_in[0];
    const float* k   = (const float*)d_in[1];
    const float* v   = (const float*)d_in[2];
    const float* Wq  = (const float*)d_in[3];
    const float* bq  = (const float*)d_in[4];
    const float* Wk  = (const float*)d_in[5];
    const float* bk  = (const float*)d_in[6];
    const float* Wv  = (const float*)d_in[7];
    const float* bv  = (const float*)d_in[8];

    const int B = 4, S = 2048, D = 1024;
    const int BS = B * S; // 8192

    // workspace layout (bf16): Qp[8192,1024] Kp[8192,1024] VpT[4][1024][2048] Sc[4][2048][2048]
    bf16_t* Qp  = (bf16_t*)d_ws;
    bf16_t* Kp  = Qp  + (size_t)BS * D;
    bf16_t* VpT = Kp  + (size_t)BS * D;
    bf16_t* Sc  = VpT + (size_t)BS * D;

    dim3 blk(256);

    // Qp = q @ Wq^T + bq   [M=8192, N=1024, K=1024], bf16 out, col bias
    gemm_nt<true, true, false, false, 1>
        <<<dim3(D / TILE, BS / TILE, 1), blk, 0, stream>>>(
            q, Wq, bq, Qp, BS, D, D, 0L, 0L, 0L, D);

    // Kp = k @ Wk^T + bk
    gemm_nt<true, true, false, false, 1>
        <<<dim3(D / TILE, BS / TILE, 1), blk, 0, stream>>>(
            k, Wk, bk, Kp, BS, D, D, 0L, 0L, 0L, D);

    // VpT[b] = (v_b @ Wv^T + bv)^T computed directly: A=Wv [1024,1024], B=v_b [2048,1024]
    // -> C[e,s], row bias bv[e].  [M=1024, N=2048, K=1024] per batch
    gemm_nt<true, true, false, false, 2>
        <<<dim3(S / TILE, D / TILE, B), blk, 0, stream>>>(
            Wv, v, bv, VpT, D, S, D, 0L, (long)S * D, (long)D * S, S);

    // Sc[b] = relu(Qp_b @ Kp_b^T)  [M=2048, N=2048, K=1024] per batch, bf16 out
    gemm_nt<false, false, false, true, 0>
        <<<dim3(S / TILE, S / TILE, B), blk, 0, stream>>>(
            Qp, Kp, nullptr, Sc, S, S, D, (long)S * D, (long)S * D, (long)S * S, S);

    // out[b] = Sc_b @ VpT_b^T  [M=2048, N=1024, K=2048] per batch, fp32 out
    gemm_nt<false, false, true, false, 0>
        <<<dim3(D / TILE, S / TILE, B), blk, 0, stream>>>(
            Sc, VpT, nullptr, d_out, S, D, S, (long)S * S, (long)D * S, (long)S * D, D);
}

// Round 2
// 332.534 us; speedup vs baseline: 1.1636x; 1.1636x over previous
//
#include <hip/hip_runtime.h>
#include <hip/hip_bf16.h>
#include <stdint.h>

typedef __bf16 bf16_t;
typedef __bf16 bf16x8 __attribute__((ext_vector_type(8)));
typedef float f32x4 __attribute__((ext_vector_type(4)));

#define TILE 128
#define BK 32

// async 16B global -> LDS (global_load_lds_dwordx4).
// LDS dest must be wave-uniform base + lane*16 -- our chunk layout guarantees it.
__device__ __forceinline__ void async_copy16(const bf16_t* g, bf16_t* l) {
    __builtin_amdgcn_global_load_lds(
        (const __attribute__((address_space(1))) unsigned int*)(uintptr_t)g,
        (__attribute__((address_space(3))) unsigned int*)(uintptr_t)l,
        16, 0, 0);
}

// NT GEMM, all-bf16 operands: C[m,n] = op( sum_k A[m,k]*B[n,k] + bias )
// A: M x K row-major, B: N x K row-major (both k-contiguous).
// 128x128 tile, 256 threads = 4 waves (2x2), each wave 64x64 via 4x4 MFMA 16x16x32.
// Staging: 8KB per tile = 512 16B-chunks; thread t loads chunks {t, t+256}.
// chunk c -> LDS byte offset c*16 (row=c>>2, colE=(c&3)*8) -- exactly lane-linear.
// BIAS_MODE: 0=none, 1=bias[col], 2=bias[row]
template<bool OUT_F32, bool RELU, int BIAS_MODE>
__global__ __launch_bounds__(256, 2)
void gemm_bt(const bf16_t* __restrict__ A, const bf16_t* __restrict__ B,
             const float* __restrict__ bias, void* __restrict__ Cp,
             int K, int ldc, long sAb, long sBb, long sCb)
{
    __shared__ bf16_t As[TILE * BK];
    __shared__ bf16_t Bs[TILE * BK];

    const int b      = blockIdx.z;
    const int blockM = blockIdx.y * TILE;
    const int blockN = blockIdx.x * TILE;
    const int t      = threadIdx.x;
    const int lane   = t & 63;
    const int wave   = t >> 6;
    const int wm     = (wave >> 1) * 64;
    const int wn     = (wave & 1) * 64;
    const int fr     = lane & 15;
    const int fk     = (lane >> 4) * 8;
    const int quad   = lane >> 4;

    f32x4 acc[4][4] = {};

    const bf16_t* Ab = A + sAb * (long)b;
    const bf16_t* Bb = B + sBb * (long)b;

    // staging chunk addresses (hoisted; k0 added per iteration)
    const int c0 = t, c1 = t + 256;
    const int r0 = c0 >> 2, e0 = (c0 & 3) * 8;
    const int r1 = c1 >> 2, e1 = (c1 & 3) * 8;
    const bf16_t* a0 = Ab + (long)(blockM + r0) * K + e0;
    const bf16_t* a1 = Ab + (long)(blockM + r1) * K + e1;
    const bf16_t* b0 = Bb + (long)(blockN + r0) * K + e0;
    const bf16_t* b1 = Bb + (long)(blockN + r1) * K + e1;
    bf16_t* lA0 = &As[c0 * 8]; bf16_t* lA1 = &As[c1 * 8];
    bf16_t* lB0 = &Bs[c0 * 8]; bf16_t* lB1 = &Bs[c1 * 8];

    for (int k0 = 0; k0 < K; k0 += BK) {
        async_copy16(a0 + k0, lA0);
        async_copy16(a1 + k0, lA1);
        async_copy16(b0 + k0, lB0);
        async_copy16(b1 + k0, lB1);
        __syncthreads();   // compiler emits s_waitcnt vmcnt(0) before s_barrier

        bf16x8 afr[4], bfr[4];
        #pragma unroll
        for (int i = 0; i < 4; i++)
            afr[i] = *(const bf16x8*)&As[(wm + i*16 + fr) * BK + fk];
        #pragma unroll
        for (int j = 0; j < 4; j++)
            bfr[j] = *(const bf16x8*)&Bs[(wn + j*16 + fr) * BK + fk];

        #pragma unroll
        for (int i = 0; i < 4; i++)
            #pragma unroll
            for (int j = 0; j < 4; j++)
                acc[i][j] = __builtin_amdgcn_mfma_f32_16x16x32_bf16(
                                afr[i], bfr[j], acc[i][j], 0, 0, 0);
        __syncthreads();
    }

    float*  Cf = (float*) Cp + sCb * (long)b;
    bf16_t* Ch = (bf16_t*)Cp + sCb * (long)b;
    #pragma unroll
    for (int i = 0; i < 4; i++) {
        #pragma unroll
        for (int j = 0; j < 4; j++) {
            const int gcol = blockN + wn + j*16 + fr;
            float bcol = 0.f;
            if (BIAS_MODE == 1) bcol = bias[gcol];
            #pragma unroll
            for (int r = 0; r < 4; r++) {
                const int grow = blockM + wm + i*16 + quad*4 + r;
                float vv = acc[i][j][r];
                if (BIAS_MODE == 1) vv += bcol;
                if (BIAS_MODE == 2) vv += bias[grow];
                if (RELU) vv = fmaxf(vv, 0.f);
                if (OUT_F32) Cf[(long)grow * ldc + gcol] = vv;
                else         Ch[(long)grow * ldc + gcol] = (bf16_t)vv;
            }
        }
    }
}

// One-shot fp32 -> bf16 cast of q,k,v,Wq,Wk,Wv into workspace.
// Each thread converts 8 consecutive floats (2x float4 load, 1x 16B store).
__global__ __launch_bounds__(256)
void cast_all_kernel(const float* __restrict__ q, const float* __restrict__ k,
                     const float* __restrict__ v, const float* __restrict__ Wq,
                     const float* __restrict__ Wk, const float* __restrict__ Wv,
                     bf16_t* __restrict__ ws)
{
    const long BIG = 1048576;   // 8192*1024 / 8
    const long SMALL = 131072;  // 1024*1024 / 8
    long id = (long)blockIdx.x * blockDim.x + threadIdx.x;
    const float* src; bf16_t* dst;
    if (id < 3 * BIG) {
        int s = (int)(id / BIG);
        long off = (id - (long)s * BIG) * 8;
        src = (s == 0 ? q : s == 1 ? k : v) + off;
        dst = ws + (long)s * 8388608 + off;
    } else {
        long id2 = id - 3 * BIG;
        int s = (int)(id2 / SMALL);
        long off = (id2 - (long)s * SMALL) * 8;
        src = (s == 0 ? Wq : s == 1 ? Wk : Wv) + off;
        dst = ws + 25165824L + (long)s * 1048576 + off;
    }
    float4 v0 = ((const float4*)src)[0];
    float4 v1 = ((const float4*)src)[1];
    alignas(16) bf16_t o[8];
    o[0]=(bf16_t)v0.x; o[1]=(bf16_t)v0.y; o[2]=(bf16_t)v0.z; o[3]=(bf16_t)v0.w;
    o[4]=(bf16_t)v1.x; o[5]=(bf16_t)v1.y; o[6]=(bf16_t)v1.z; o[7]=(bf16_t)v1.w;
    *(uint4*)dst = *(const uint4*)o;
}

extern "C" void kernel_launch(void* const* d_in, const int* in_sizes, int n_in,
                              void* d_out, int out_size, void* d_ws, size_t ws_size,
                              hipStream_t stream)
{
    const float* q   = (const float*)d_in[0];
    const float* k   = (const float*)d_in[1];
    const float* v   = (const float*)d_in[2];
    const float* Wq  = (const float*)d_in[3];
    const float* bq  = (const float*)d_in[4];
    const float* Wk  = (const float*)d_in[5];
    const float* bk  = (const float*)d_in[6];
    const float* Wv  = (const float*)d_in[7];
    const float* bv  = (const float*)d_in[8];

    const int B = 4, S = 2048, D = 1024;
    const int BS = B * S; // 8192

    // workspace layout (bf16 element offsets):
    //   qb 0          (8388608)   -- dead after step1; Sc aliases [0, 16777216)
    //   kb 8388608    (8388608)   -- dead after step2
    //   vb 16777216   (8388608)   -- dead after step3
    //   Wqb 25165824  (1048576)
    //   Wkb 26214400  (1048576)
    //   Wvb 27262976  (1048576)
    //   Qp  28311552  (8388608)
    //   Kp  36700160  (8388608)
    //   VpT 45088768  (8388608)   total 53477376 elems = ~107 MB
    bf16_t* ws  = (bf16_t*)d_ws;
    bf16_t* qb  = ws;
    bf16_t* kb  = ws + 8388608L;
    bf16_t* vb  = ws + 16777216L;
    bf16_t* Wqb = ws + 25165824L;
    bf16_t* Wkb = ws + 26214400L;
    bf16_t* Wvb = ws + 27262976L;
    bf16_t* Qp  = ws + 28311552L;
    bf16_t* Kp  = ws + 36700160L;
    bf16_t* VpT = ws + 45088768L;
    bf16_t* Sc  = ws;              // aliases qb+kb (both dead by step 4)

    dim3 blk(256);

    // cast everything to bf16: 3538944 threads = 13824 blocks
    cast_all_kernel<<<dim3(13824), blk, 0, stream>>>(q, k, v, Wq, Wk, Wv, ws);

    // Qp = qb @ Wqb^T + bq   [M=8192, N=1024, K=1024]
    gemm_bt<false, false, 1><<<dim3(D / TILE, BS / TILE, 1), blk, 0, stream>>>(
        qb, Wqb, bq, Qp, D, D, 0L, 0L, 0L);

    // Kp = kb @ Wkb^T + bk
    gemm_bt<false, false, 1><<<dim3(D / TILE, BS / TILE, 1), blk, 0, stream>>>(
        kb, Wkb, bk, Kp, D, D, 0L, 0L, 0L);

    // VpT[b] = (v_b @ Wv^T + bv)^T : A=Wvb [1024,1024], B=vb_b [2048,1024], row bias
    gemm_bt<false, false, 2><<<dim3(S / TILE, D / TILE, B), blk, 0, stream>>>(
        Wvb, vb, bv, VpT, D, S, 0L, (long)S * D, (long)D * S);

    // Sc[b] = relu(Qp_b @ Kp_b^T)  [2048 x 2048, K=1024], bf16 out
    gemm_bt<false, true, 0><<<dim3(S / TILE, S / TILE, B), blk, 0, stream>>>(
        Qp, Kp, nullptr, Sc, D, S, (long)S * D, (long)S * D, (long)S * S);

    // out[b] = Sc_b @ VpT_b^T  [2048 x 1024, K=2048], fp32 out
    gemm_bt<false /*unused*/ || true, false, 0><<<dim3(D / TILE, S / TILE, B), blk, 0, stream>>>(
        Sc, VpT, nullptr, d_out, S, D, (long)S * S, (long)D * S, (long)S * D);
}

// Round 3
// 309.875 us; speedup vs baseline: 1.2487x; 1.0731x over previous
//
#include <hip/hip_runtime.h>
#include <hip/hip_bf16.h>
#include <stdint.h>

typedef __bf16 bf16_t;
typedef __bf16 bf16x8 __attribute__((ext_vector_type(8)));
typedef float f32x16 __attribute__((ext_vector_type(16)));

#define TILE 128
#define BK 64   // 128x64 bf16 tile = 16 KB per matrix, 32 KB LDS total

// async 16B global -> LDS (global_load_lds_dwordx4).
// LDS dest must be wave-uniform base + lane*16 -- chunk layout guarantees it.
__device__ __forceinline__ void async_copy16(const bf16_t* g, bf16_t* l) {
    __builtin_amdgcn_global_load_lds(
        (const __attribute__((address_space(1))) unsigned int*)(uintptr_t)g,
        (__attribute__((address_space(3))) unsigned int*)(uintptr_t)l,
        16, 0, 0);
}

// NT GEMM, all-bf16: C[m,n] = op( sum_k A[m,k]*B[n,k] + bias )
// 128x128 tile, 256 thr = 4 waves (2x2), each wave 64x64 via 2x2 MFMA 32x32x16.
// LDS: 8-element chunks, XOR-swizzled: chunk (row,kc) stored at index row*8+(kc^(row&7)).
// Staging thread t loads stored-chunks {t+j*256}, computing the matching global kc.
// BIAS_MODE: 0=none, 1=bias[col], 2=bias[row]
template<bool OUT_F32, bool RELU, int BIAS_MODE>
__global__ __launch_bounds__(256, 2)
void gemm_bt(const bf16_t* __restrict__ A, const bf16_t* __restrict__ B,
             const float* __restrict__ bias, void* __restrict__ Cp,
             int K, int ldc, long sAb, long sBb, long sCb)
{
    __shared__ bf16_t As[TILE * BK];
    __shared__ bf16_t Bs[TILE * BK];

    const int b  = blockIdx.z;
    // supertile swizzle: sweep all M for a strip of SW n-columns (L2 locality)
    const int nb = gridDim.x, mb = gridDim.y;
    const int SW = 4;
    int bid   = blockIdx.y * nb + blockIdx.x;
    int strip = bid / (mb * SW);
    int rem   = bid - strip * (mb * SW);
    int bm    = rem / SW;
    int bn    = strip * SW + (rem - bm * SW);
    const int blockM = bm * TILE;
    const int blockN = bn * TILE;

    const int t    = threadIdx.x;
    const int lane = t & 63;
    const int wave = t >> 6;
    const int wm   = (wave >> 1) * 64;
    const int wn   = (wave & 1) * 64;
    const int r32  = lane & 31;       // row within 32x32 tile (A) / col (B)
    const int half = lane >> 5;       // k-half selector
    const int kx   = r32 & 7;         // xor key for swizzled frag reads

    f32x16 acc[2][2] = {};

    const bf16_t* Ab = A + sAb * (long)b;
    const bf16_t* Bb = B + sBb * (long)b;

    // staging addresses: stored chunk c = t + j*256; row=c>>3, stored kc=c&7,
    // logical kc = stored^ (row&7). 4 chunks each for A and B per K-step.
    const bf16_t* gA[4]; const bf16_t* gB[4];
    bf16_t* lA[4]; bf16_t* lB[4];
    #pragma unroll
    for (int j = 0; j < 4; j++) {
        int c   = t + j * 256;
        int row = c >> 3;
        int kcl = (c & 7) ^ (row & 7);
        gA[j] = Ab + (long)(blockM + row) * K + kcl * 8;
        gB[j] = Bb + (long)(blockN + row) * K + kcl * 8;
        lA[j] = &As[c * 8];
        lB[j] = &Bs[c * 8];
    }

    for (int k0 = 0; k0 < K; k0 += BK) {
        #pragma unroll
        for (int j = 0; j < 4; j++) async_copy16(gA[j] + k0, lA[j]);
        #pragma unroll
        for (int j = 0; j < 4; j++) async_copy16(gB[j] + k0, lB[j]);
        __syncthreads();

        #pragma unroll
        for (int ks = 0; ks < 4; ks++) {
            const int kc = ks * 2 + half;       // logical 8-elem chunk in BK
            bf16x8 af[2], bfr[2];
            #pragma unroll
            for (int i = 0; i < 2; i++) {
                int R = wm + i * 32 + r32;
                af[i] = *(const bf16x8*)&As[(R * 8 + (kc ^ kx)) * 8];
            }
            #pragma unroll
            for (int j = 0; j < 2; j++) {
                int C = wn + j * 32 + r32;
                bfr[j] = *(const bf16x8*)&Bs[(C * 8 + (kc ^ kx)) * 8];
            }
            #pragma unroll
            for (int i = 0; i < 2; i++)
                #pragma unroll
                for (int j = 0; j < 2; j++)
                    acc[i][j] = __builtin_amdgcn_mfma_f32_32x32x16_bf16(
                                    af[i], bfr[j], acc[i][j], 0, 0, 0);
        }
        __syncthreads();
    }

    // epilogue: C/D layout col=lane&31, row=(reg&3)+8*(reg>>2)+4*half
    float*  Cf = (float*) Cp + sCb * (long)b;
    bf16_t* Ch = (bf16_t*)Cp + sCb * (long)b;
    #pragma unroll
    for (int ti = 0; ti < 2; ti++) {
        #pragma unroll
        for (int tj = 0; tj < 2; tj++) {
            const int gcol = blockN + wn + tj * 32 + r32;
            float bc = 0.f;
            if (BIAS_MODE == 1) bc = bias[gcol];
            #pragma unroll
            for (int reg = 0; reg < 16; reg++) {
                const int grow = blockM + wm + ti * 32
                               + (reg & 3) + 8 * (reg >> 2) + 4 * half;
                float vv = acc[ti][tj][reg];
                if (BIAS_MODE == 1) vv += bc;
                if (BIAS_MODE == 2) vv += bias[grow];
                if (RELU) vv = fmaxf(vv, 0.f);
                if (OUT_F32) Cf[(long)grow * ldc + gcol] = vv;
                else         Ch[(long)grow * ldc + gcol] = (bf16_t)vv;
            }
        }
    }
}

// One-shot fp32 -> bf16 cast of q,k,v,Wq,Wk,Wv into workspace.
__global__ __launch_bounds__(256)
void cast_all_kernel(const float* __restrict__ q, const float* __restrict__ k,
                     const float* __restrict__ v, const float* __restrict__ Wq,
                     const float* __restrict__ Wk, const float* __restrict__ Wv,
                     bf16_t* __restrict__ ws)
{
    const long BIG = 1048576;   // 8192*1024 / 8
    const long SMALL = 131072;  // 1024*1024 / 8
    long id = (long)blockIdx.x * blockDim.x + threadIdx.x;
    const float* src; bf16_t* dst;
    if (id < 3 * BIG) {
        int s = (int)(id / BIG);
        long off = (id - (long)s * BIG) * 8;
        src = (s == 0 ? q : s == 1 ? k : v) + off;
        dst = ws + (long)s * 8388608 + off;
    } else {
        long id2 = id - 3 * BIG;
        int s = (int)(id2 / SMALL);
        long off = (id2 - (long)s * SMALL) * 8;
        src = (s == 0 ? Wq : s == 1 ? Wk : Wv) + off;
        dst = ws + 25165824L + (long)s * 1048576 + off;
    }
    float4 v0 = ((const float4*)src)[0];
    float4 v1 = ((const float4*)src)[1];
    alignas(16) bf16_t o[8];
    o[0]=(bf16_t)v0.x; o[1]=(bf16_t)v0.y; o[2]=(bf16_t)v0.z; o[3]=(bf16_t)v0.w;
    o[4]=(bf16_t)v1.x; o[5]=(bf16_t)v1.y; o[6]=(bf16_t)v1.z; o[7]=(bf16_t)v1.w;
    *(uint4*)dst = *(const uint4*)o;
}

extern "C" void kernel_launch(void* const* d_in, const int* in_sizes, int n_in,
                              void* d_out, int out_size, void* d_ws, size_t ws_size,
                              hipStream_t stream)
{
    const float* q   = (const float*)d_in[0];
    const float* k   = (const float*)d_in[1];
    const float* v   = (const float*)d_in[2];
    const float* Wq  = (const float*)d_in[3];
    const float* bq  = (const float*)d_in[4];
    const float* Wk  = (const float*)d_in[5];
    const float* bk  = (const float*)d_in[6];
    const float* Wv  = (const float*)d_in[7];
    const float* bv  = (const float*)d_in[8];

    const int B = 4, S = 2048, D = 1024;
    const int BS = B * S; // 8192

    // workspace layout (bf16 element offsets):
    //   qb 0, kb 8388608, vb 16777216 (dead after their GEMM; Sc aliases qb+kb)
    //   Wqb 25165824, Wkb 26214400, Wvb 27262976
    //   Qp 28311552, Kp 36700160, VpT 45088768   (total ~107 MB)
    bf16_t* ws  = (bf16_t*)d_ws;
    bf16_t* qb  = ws;
    bf16_t* kb  = ws + 8388608L;
    bf16_t* vb  = ws + 16777216L;
    bf16_t* Wqb = ws + 25165824L;
    bf16_t* Wkb = ws + 26214400L;
    bf16_t* Wvb = ws + 27262976L;
    bf16_t* Qp  = ws + 28311552L;
    bf16_t* Kp  = ws + 36700160L;
    bf16_t* VpT = ws + 45088768L;
    bf16_t* Sc  = ws;              // aliases qb+kb (both dead by step 4)

    dim3 blk(256);

    cast_all_kernel<<<dim3(13824), blk, 0, stream>>>(q, k, v, Wq, Wk, Wv, ws);

    // Qp = qb @ Wqb^T + bq   [M=8192, N=1024, K=1024]
    gemm_bt<false, false, 1><<<dim3(D / TILE, BS / TILE, 1), blk, 0, stream>>>(
        qb, Wqb, bq, Qp, D, D, 0L, 0L, 0L);

    // Kp = kb @ Wkb^T + bk
    gemm_bt<false, false, 1><<<dim3(D / TILE, BS / TILE, 1), blk, 0, stream>>>(
        kb, Wkb, bk, Kp, D, D, 0L, 0L, 0L);

    // VpT[b] = (v_b @ Wv^T + bv)^T : A=Wvb [1024,1024], B=vb_b [2048,1024], row bias
    gemm_bt<false, false, 2><<<dim3(S / TILE, D / TILE, B), blk, 0, stream>>>(
        Wvb, vb, bv, VpT, D, S, 0L, (long)S * D, (long)D * S);

    // Sc[b] = relu(Qp_b @ Kp_b^T)  [2048 x 2048, K=1024], bf16 out
    gemm_bt<false, true, 0><<<dim3(S / TILE, S / TILE, B), blk, 0, stream>>>(
        Qp, Kp, nullptr, Sc, D, S, (long)S * D, (long)S * D, (long)S * S);

    // out[b] = Sc_b @ VpT_b^T  [2048 x 1024, K=2048], fp32 out
    gemm_bt<true, false, 0><<<dim3(D / TILE, S / TILE, B), blk, 0, stream>>>(
        Sc, VpT, nullptr, d_out, S, D, (long)S * S, (long)D * S, (long)S * D);
}